// Round 1
// baseline (620.249 us; speedup 1.0000x reference)
//
#include <hip/hip_runtime.h>

#define H_  192
#define W_  192
#define HW  36864
#define B_  4
#define C_  64

// ---------------- ws layout (float offsets) ----------------
// offset  [B,18,H,W]        @ 0          size 2654208
// w_t     [9][64][64]       @ 2654208    size 36864
// scale   [64]              @ 2691072
// shift   [64]              @ 2691136
// cw      [B*64]            @ 2691200
// partial [2304*64]         @ 2691456    size 147456
// sw      [B*H*W]           @ 2838912    size 147456
// total 2986368 floats = 11.95 MB

// K0: transpose dw -> w_t[tap][c][o]; fold BN+bias into scale/shift
__global__ void prep_kernel(const float* __restrict__ dw, const float* __restrict__ db,
                            const float* __restrict__ g, const float* __restrict__ be,
                            const float* __restrict__ mu, const float* __restrict__ var,
                            float* __restrict__ w_t, float* __restrict__ scale,
                            float* __restrict__ shift) {
    int idx = blockIdx.x * 256 + threadIdx.x;
    if (idx < 9 * 64 * 64) {
        int tap = idx >> 12;
        int c = (idx >> 6) & 63;
        int o = idx & 63;
        w_t[idx] = dw[(o * 64 + c) * 9 + tap];
    }
    if (blockIdx.x == 0 && threadIdx.x < 64) {
        int o = threadIdx.x;
        float s = g[o] * rsqrtf(var[o] + 1e-5f);
        scale[o] = s;
        shift[o] = (db[o] - mu[o]) * s + be[o];
    }
}

// K1: offset-prediction conv 3x3, 64->18 ch. One block per (y,b) row, thread=x.
// acc[18] in VGPRs; weights are lane-uniform -> scalar loads.
__global__ __launch_bounds__(192) void offset_conv_kernel(
    const float* __restrict__ x, const float* __restrict__ ow,
    const float* __restrict__ ob, float* __restrict__ offset) {
    int xx = threadIdx.x;
    int y = blockIdx.x;
    int b = blockIdx.y;
    float acc[18];
#pragma unroll
    for (int oc = 0; oc < 18; ++oc) acc[oc] = ob[oc];
    for (int c = 0; c < 64; ++c) {
        const float* xc = x + (size_t)(b * 64 + c) * HW;
#pragma unroll
        for (int i = 0; i < 3; ++i) {
            int yy = y + i - 1;
            if (yy < 0 || yy >= H_) continue;
            const float* row = xc + yy * W_;
#pragma unroll
            for (int j = 0; j < 3; ++j) {
                int xj = xx + j - 1;
                float v = (xj >= 0 && xj < W_) ? row[xj] : 0.0f;
#pragma unroll
                for (int oc = 0; oc < 18; ++oc)
                    acc[oc] += v * ow[(oc * 64 + c) * 9 + i * 3 + j];
            }
        }
    }
#pragma unroll
    for (int oc = 0; oc < 18; ++oc)
        offset[((b * 18 + oc) * H_ + y) * W_ + xx] = acc[oc];
}

// K2: deformable conv as implicit GEMM (M=64 oc, N=64 positions/block, K=9taps*64c),
// fused BN epilogue + per-block channel partial sums.
__global__ __launch_bounds__(256) void deform_kernel(
    const float* __restrict__ x, const float* __restrict__ offset,
    const float* __restrict__ w_t, const float* __restrict__ scale_g,
    const float* __restrict__ shift_g, float* __restrict__ out,
    float* __restrict__ partial) {
    __shared__ float w_lds[4096];   // [c][o]
    __shared__ float s_lds[4096];   // [c][n]
    __shared__ int   cy[64];
    __shared__ int   cx[64];
    __shared__ float cwy[64];
    __shared__ float cwx[64];
    __shared__ float red[1024];     // [o][16]

    int tid = threadIdx.x;
    int tile = blockIdx.x;
    int b = tile / 576;
    int rrr = tile % 576;
    int y = rrr / 3;
    int x0 = (rrr % 3) * 64;

    int to = tid & 15, tn = tid >> 4;
    int o0 = to * 4, n0 = tn * 4;
    float acc[4][4] = {};

    int n_lane = tid & 63;
    int c_grp = (tid >> 6) * 16;

    for (int tap = 0; tap < 9; ++tap) {
        int ti = tap / 3, tj = tap % 3;
        // phase A: per-position sampling corners (once per tap, shared over all c)
        if (tid < 64) {
            int xx = x0 + tid;
            float ody = offset[((b * 18 + 2 * tap) * H_ + y) * W_ + xx];
            float odx = offset[((b * 18 + 2 * tap + 1) * H_ + y) * W_ + xx];
            float py = (float)(y + ti - 1) + ody;
            float px = (float)(xx + tj - 1) + odx;
            float fy = floorf(py), fx = floorf(px);
            cy[tid] = (int)fy;
            cx[tid] = (int)fx;
            cwy[tid] = py - fy;
            cwx[tid] = px - fx;
        }
        // phase B: stage this tap's weight slice (coalesced from pre-transposed w_t)
#pragma unroll
        for (int q = 0; q < 4; ++q) {
            int idx = (tid + q * 256) * 4;
            *(float4*)&w_lds[idx] = *(const float4*)&w_t[tap * 4096 + idx];
        }
        __syncthreads();
        // phase C: bilinear gather samp[c][n] -> LDS (corner math hoisted out of c-loop)
        {
            int y0 = cy[n_lane], x0i = cx[n_lane];
            float wy = cwy[n_lane], wx = cwx[n_lane];
            int y0c = min(max(y0, 0), H_ - 1), y1c = min(max(y0 + 1, 0), H_ - 1);
            int x0c = min(max(x0i, 0), W_ - 1), x1c = min(max(x0i + 1, 0), W_ - 1);
            float vy0 = (y0 >= 0 && y0 < H_) ? 1.f : 0.f;
            float vy1 = (y0 + 1 >= 0 && y0 + 1 < H_) ? 1.f : 0.f;
            float vx0 = (x0i >= 0 && x0i < W_) ? 1.f : 0.f;
            float vx1 = (x0i + 1 >= 0 && x0i + 1 < W_) ? 1.f : 0.f;
            float w00 = (1.f - wy) * (1.f - wx) * vy0 * vx0;
            float w01 = (1.f - wy) * wx * vy0 * vx1;
            float w10 = wy * (1.f - wx) * vy1 * vx0;
            float w11 = wy * wx * vy1 * vx1;
            int i00 = y0c * W_ + x0c, i01 = y0c * W_ + x1c;
            int i10 = y1c * W_ + x0c, i11 = y1c * W_ + x1c;
            const float* xb = x + (size_t)(b * 64 + c_grp) * HW;
#pragma unroll 4
            for (int q = 0; q < 16; ++q) {
                float v = w00 * xb[i00] + w01 * xb[i01] + w10 * xb[i10] + w11 * xb[i11];
                s_lds[(c_grp + q) * 64 + n_lane] = v;
                xb += HW;
            }
        }
        __syncthreads();
        // phase D: register-blocked GEMM 4o x 4n per thread
#pragma unroll 4
        for (int k = 0; k < 64; ++k) {
            float4 a = *(const float4*)&w_lds[k * 64 + o0];
            float4 bb = *(const float4*)&s_lds[k * 64 + n0];
            float av[4] = {a.x, a.y, a.z, a.w};
            float bv[4] = {bb.x, bb.y, bb.z, bb.w};
#pragma unroll
            for (int i2 = 0; i2 < 4; ++i2)
#pragma unroll
                for (int j2 = 0; j2 < 4; ++j2) acc[i2][j2] += av[i2] * bv[j2];
        }
        __syncthreads();
    }
    // epilogue: BN affine, store, per-block channel sums
#pragma unroll
    for (int i2 = 0; i2 < 4; ++i2) {
        int o = o0 + i2;
        float sc = scale_g[o], sh = shift_g[o];
        float v0 = acc[i2][0] * sc + sh;
        float v1 = acc[i2][1] * sc + sh;
        float v2 = acc[i2][2] * sc + sh;
        float v3 = acc[i2][3] * sc + sh;
        float* orow = out + (size_t)(b * 64 + o) * HW + y * W_ + x0 + n0;
        *(float4*)orow = make_float4(v0, v1, v2, v3);
        red[o * 16 + tn] = v0 + v1 + v2 + v3;
    }
    __syncthreads();
    if (tid < 64) {
        float s = 0.f;
#pragma unroll 4
        for (int q = 0; q < 16; ++q) s += red[tid * 16 + q];
        partial[tile * 64 + tid] = s;
    }
}

// K3: pooled mean (reduce partials) -> squeeze/excite MLP -> cw[b,c]
__global__ void ca_kernel(const float* __restrict__ partial,
                          const float* __restrict__ w1, const float* __restrict__ b1,
                          const float* __restrict__ w2, const float* __restrict__ b2,
                          float* __restrict__ cw) {
    __shared__ float pooled[256];
    __shared__ float t1[16];
    int t = threadIdx.x;
    int b = t >> 6, o = t & 63;
    float s = 0.f;
    for (int blk = 0; blk < 576; ++blk) s += partial[(b * 576 + blk) * 64 + o];
    pooled[t] = s * (1.0f / (float)HW);
    __syncthreads();
    if (t < 16) {
        int bb = t >> 2, hh = t & 3;
        float a = b1[hh];
        for (int c = 0; c < 64; ++c) a += pooled[bb * 64 + c] * w1[hh * 64 + c];
        t1[t] = fmaxf(a, 0.f);
    }
    __syncthreads();
    {
        float a = b2[o];
#pragma unroll
        for (int h2 = 0; h2 < 4; ++h2) a += t1[b * 4 + h2] * w2[o * 4 + h2];
        cw[t] = 1.f / (1.f + __expf(-a));
    }
}

// K4: spatial attention 7x7 conv over (h*cw) via cw-scaled weights; sw to ws.
__global__ __launch_bounds__(192) void sa_kernel(
    const float* __restrict__ h, const float* __restrict__ saw,
    const float* __restrict__ sab, const float* __restrict__ cw,
    float* __restrict__ sw) {
    __shared__ float we[64 * 56];  // [c][dy*8+dx], dx padded to 8
    int x = threadIdx.x, y = blockIdx.x, b = blockIdx.y;
    for (int idx = threadIdx.x; idx < 64 * 56; idx += 192) {
        int c = idx / 56, rr = idx % 56, dy = rr >> 3, dx = rr & 7;
        we[idx] = (dx < 7) ? cw[b * 64 + c] * saw[c * 49 + dy * 7 + dx] : 0.f;
    }
    __syncthreads();
    float acc = sab[0];
    for (int c = 0; c < 64; ++c) {
        const float* hb = h + (size_t)(b * 64 + c) * HW;
#pragma unroll
        for (int dy = 0; dy < 7; ++dy) {
            int yy = y + dy - 3;
            if (yy < 0 || yy >= H_) continue;
            const float* row = hb + yy * W_;
#pragma unroll
            for (int dx = 0; dx < 7; ++dx) {
                int xj = x + dx - 3;
                float v = (xj >= 0 && xj < W_) ? row[xj] : 0.f;
                acc += v * we[c * 56 + dy * 8 + dx];
            }
        }
    }
    sw[(b * H_ + y) * W_ + x] = 1.f / (1.f + __expf(-acc));
}

// K5: out = h * cw[b,c] * sw[b,y,x]  (in-place on d_out)
__global__ void final_kernel(float* __restrict__ out, const float* __restrict__ cw,
                             const float* __restrict__ sw) {
    int idx = blockIdx.x * 256 + threadIdx.x;  // float4 index
    int e = idx * 4;
    int b = e / (64 * HW);
    int r = e % (64 * HW);
    int c = r / HW;
    int p = r % HW;
    float cwv = cw[b * 64 + c];
    float4 h4 = *(float4*)(out + e);
    float4 s4 = *(const float4*)(sw + b * HW + p);
    float4 o4;
    o4.x = h4.x * cwv * s4.x;
    o4.y = h4.y * cwv * s4.y;
    o4.z = h4.z * cwv * s4.z;
    o4.w = h4.w * cwv * s4.w;
    *(float4*)(out + e) = o4;
}

extern "C" void kernel_launch(void* const* d_in, const int* in_sizes, int n_in,
                              void* d_out, int out_size, void* d_ws, size_t ws_size,
                              hipStream_t stream) {
    const float* x     = (const float*)d_in[0];
    const float* off_w = (const float*)d_in[1];
    const float* off_b = (const float*)d_in[2];
    const float* dw    = (const float*)d_in[3];
    const float* db    = (const float*)d_in[4];
    const float* bn_g  = (const float*)d_in[5];
    const float* bn_b  = (const float*)d_in[6];
    const float* bn_m  = (const float*)d_in[7];
    const float* bn_v  = (const float*)d_in[8];
    const float* ca_w1 = (const float*)d_in[9];
    const float* ca_b1 = (const float*)d_in[10];
    const float* ca_w2 = (const float*)d_in[11];
    const float* ca_b2 = (const float*)d_in[12];
    const float* sa_w  = (const float*)d_in[13];
    const float* sa_b  = (const float*)d_in[14];
    float* out = (float*)d_out;
    float* ws  = (float*)d_ws;

    float* offset  = ws;
    float* w_t     = ws + 2654208;
    float* scale   = ws + 2691072;
    float* shift   = ws + 2691136;
    float* cw      = ws + 2691200;
    float* partial = ws + 2691456;
    float* sw      = ws + 2838912;

    prep_kernel<<<144, 256, 0, stream>>>(dw, db, bn_g, bn_b, bn_m, bn_v, w_t, scale, shift);
    offset_conv_kernel<<<dim3(192, 4), 192, 0, stream>>>(x, off_w, off_b, offset);
    deform_kernel<<<2304, 256, 0, stream>>>(x, offset, w_t, scale, shift, out, partial);
    ca_kernel<<<1, 256, 0, stream>>>(partial, ca_w1, ca_b1, ca_w2, ca_b2, cw);
    sa_kernel<<<dim3(192, 4), 192, 0, stream>>>(out, sa_w, sa_b, cw, sw);
    final_kernel<<<9216, 256, 0, stream>>>(out, cw, sw);
}

// Round 2
// 591.724 us; speedup vs baseline: 1.0482x; 1.0482x over previous
//
#include <hip/hip_runtime.h>

#define H_  192
#define W_  192
#define HW  36864
#define B_  4
#define C_  64

typedef __attribute__((ext_vector_type(8))) short short8;
typedef __attribute__((ext_vector_type(4))) float f32x4;

// ---------------- ws layout (float offsets) ----------------
// offset  [B,18,H,W]        @ 0          size 2654208
// w_bf    [9][64][64] bf16  @ 2654208    size 18432 floats (36864 ushort)
// scale   [64]              @ 2672640
// shift   [64]              @ 2672704
// cw      [B*64]            @ 2672768
// partial [64][1152]        @ 2673024    size 73728
// we_eff  [B*64][7][8]      @ 2746752    size 14336
// sw      [B*H*W]           @ 2761088    size 147456
// total 2908544 floats = 11.63 MB

__device__ __forceinline__ unsigned short f2bf(float v) {
    unsigned int u = __builtin_bit_cast(unsigned int, v);
    u += 0x7FFFu + ((u >> 16) & 1u);   // RNE
    return (unsigned short)(u >> 16);
}

// K0: dw -> bf16 w_bf[tap][o][c]; fold BN+bias into scale/shift
__global__ void prep_kernel(const float* __restrict__ dw, const float* __restrict__ db,
                            const float* __restrict__ g, const float* __restrict__ be,
                            const float* __restrict__ mu, const float* __restrict__ var,
                            unsigned short* __restrict__ w_bf, float* __restrict__ scale,
                            float* __restrict__ shift) {
    int idx = blockIdx.x * 256 + threadIdx.x;
    if (idx < 9 * 64 * 64) {
        int tap = idx >> 12;
        int o = (idx >> 6) & 63;
        int c = idx & 63;
        w_bf[idx] = f2bf(dw[(o * 64 + c) * 9 + tap]);
    }
    if (blockIdx.x == 0 && threadIdx.x < 64) {
        int o = threadIdx.x;
        float s = g[o] * rsqrtf(var[o] + 1e-5f);
        scale[o] = s;
        shift[o] = (db[o] - mu[o]) * s + be[o];
    }
}

// K1: offset-prediction conv 3x3, 64->18 ch (unchanged this round)
__global__ __launch_bounds__(192) void offset_conv_kernel(
    const float* __restrict__ x, const float* __restrict__ ow,
    const float* __restrict__ ob, float* __restrict__ offset) {
    int xx = threadIdx.x;
    int y = blockIdx.x;
    int b = blockIdx.y;
    float acc[18];
#pragma unroll
    for (int oc = 0; oc < 18; ++oc) acc[oc] = ob[oc];
    for (int c = 0; c < 64; ++c) {
        const float* xc = x + (size_t)(b * 64 + c) * HW;
#pragma unroll
        for (int i = 0; i < 3; ++i) {
            int yy = y + i - 1;
            if (yy < 0 || yy >= H_) continue;
            const float* row = xc + yy * W_;
#pragma unroll
            for (int j = 0; j < 3; ++j) {
                int xj = xx + j - 1;
                float v = (xj >= 0 && xj < W_) ? row[xj] : 0.0f;
#pragma unroll
                for (int oc = 0; oc < 18; ++oc)
                    acc[oc] += v * ow[(oc * 64 + c) * 9 + i * 3 + j];
            }
        }
    }
#pragma unroll
    for (int oc = 0; oc < 18; ++oc)
        offset[((b * 18 + oc) * H_ + y) * W_ + xx] = acc[oc];
}

// K2: deformable conv, bf16 MFMA implicit GEMM.
// Tile: M=64 oc x N=128 positions, K=9 taps x 64 c. 4 waves; wave owns 32 n.
// s_lds[n][c] bf16 with 16B-slot XOR swizzle: byte = n*128 + ((c/8)*16 ^ ((n&7)<<4)).
__global__ __launch_bounds__(256) void deform_kernel(
    const float* __restrict__ x, const float* __restrict__ offset,
    const unsigned short* __restrict__ w_bf, const float* __restrict__ scale_g,
    const float* __restrict__ shift_g, float* __restrict__ out,
    float* __restrict__ partial) {
    __shared__ __align__(16) unsigned short s_lds[8192];  // 16 KB
    __shared__ float red[256];                            // [m][wave]

    int tid = threadIdx.x;
    // XCD-bijective swizzle: 1152 blocks = 8 XCDs x 144 contiguous tiles
    int tile = (blockIdx.x & 7) * 144 + (blockIdx.x >> 3);
    int b = tile / 288;
    int p0 = (tile % 288) * 128;

    int n_loc = tid & 127;          // position within tile (gather role)
    int ch0 = (tid >> 7) * 32;      // 32-channel half (gather role)
    int p = p0 + n_loc;
    int y = p / 192;
    int xx = p - y * 192;

    int wid = tid >> 6, lane = tid & 63, ln = lane & 15, kg = lane >> 4;

    f32x4 acc[4][2];
#pragma unroll
    for (int mt = 0; mt < 4; ++mt)
#pragma unroll
        for (int nt = 0; nt < 2; ++nt) acc[mt][nt] = (f32x4){0.f, 0.f, 0.f, 0.f};

    const float* xb = x + (size_t)(b * 64 + ch0) * HW;

    for (int tap = 0; tap < 9; ++tap) {
        int ti = tap / 3, tj = tap % 3;
        // ---- gather phase: corners once per position, 32 c per thread ----
        {
            float ody = offset[(size_t)(b * 18 + 2 * tap) * HW + p];
            float odx = offset[(size_t)(b * 18 + 2 * tap + 1) * HW + p];
            float py = (float)(y + ti - 1) + ody;
            float px = (float)(xx + tj - 1) + odx;
            float fy = floorf(py), fx = floorf(px);
            int y0 = (int)fy, x0i = (int)fx;
            float wy = py - fy, wx = px - fx;
            int y0c = min(max(y0, 0), H_ - 1), y1c = min(max(y0 + 1, 0), H_ - 1);
            int x0c = min(max(x0i, 0), W_ - 1), x1c = min(max(x0i + 1, 0), W_ - 1);
            float vy0 = (y0 >= 0 && y0 < H_) ? 1.f : 0.f;
            float vy1 = (y0 + 1 >= 0 && y0 + 1 < H_) ? 1.f : 0.f;
            float vx0 = (x0i >= 0 && x0i < W_) ? 1.f : 0.f;
            float vx1 = (x0i + 1 >= 0 && x0i + 1 < W_) ? 1.f : 0.f;
            float w00 = (1.f - wy) * (1.f - wx) * vy0 * vx0;
            float w01 = (1.f - wy) * wx * vy0 * vx1;
            float w10 = wy * (1.f - wx) * vy1 * vx0;
            float w11 = wy * wx * vy1 * vx1;
            int i00 = y0c * W_ + x0c, i01 = y0c * W_ + x1c;
            int i10 = y1c * W_ + x0c, i11 = y1c * W_ + x1c;
#pragma unroll
            for (int cb = 0; cb < 4; ++cb) {
                short8 v8;
#pragma unroll
                for (int q = 0; q < 8; ++q) {
                    const float* xc = xb + (size_t)(cb * 8 + q) * HW;
                    float v = w00 * xc[i00] + w01 * xc[i01] + w10 * xc[i10] + w11 * xc[i11];
                    v8[q] = (short)f2bf(v);
                }
                int slot = (ch0 >> 3) + cb;
                int addr = n_loc * 128 + ((slot * 16) ^ ((n_loc & 7) << 4));
                *(short8*)((char*)s_lds + addr) = v8;
            }
        }
        __syncthreads();
        // ---- MFMA phase ----
        const unsigned short* wtap = w_bf + tap * 4096;
#pragma unroll
        for (int ks = 0; ks < 2; ++ks) {
            short8 a0 = *(const short8*)(wtap + (0 + ln) * 64 + ks * 32 + kg * 8);
            short8 a1 = *(const short8*)(wtap + (16 + ln) * 64 + ks * 32 + kg * 8);
            short8 a2 = *(const short8*)(wtap + (32 + ln) * 64 + ks * 32 + kg * 8);
            short8 a3 = *(const short8*)(wtap + (48 + ln) * 64 + ks * 32 + kg * 8);
            int cslot = ks * 4 + kg;
            int n0g = wid * 32 + ln;
            int n1g = n0g + 16;
            short8 b0 = *(const short8*)((char*)s_lds + n0g * 128 + ((cslot * 16) ^ ((n0g & 7) << 4)));
            short8 b1 = *(const short8*)((char*)s_lds + n1g * 128 + ((cslot * 16) ^ ((n1g & 7) << 4)));
            acc[0][0] = __builtin_amdgcn_mfma_f32_16x16x32_bf16(a0, b0, acc[0][0], 0, 0, 0);
            acc[0][1] = __builtin_amdgcn_mfma_f32_16x16x32_bf16(a0, b1, acc[0][1], 0, 0, 0);
            acc[1][0] = __builtin_amdgcn_mfma_f32_16x16x32_bf16(a1, b0, acc[1][0], 0, 0, 0);
            acc[1][1] = __builtin_amdgcn_mfma_f32_16x16x32_bf16(a1, b1, acc[1][1], 0, 0, 0);
            acc[2][0] = __builtin_amdgcn_mfma_f32_16x16x32_bf16(a2, b0, acc[2][0], 0, 0, 0);
            acc[2][1] = __builtin_amdgcn_mfma_f32_16x16x32_bf16(a2, b1, acc[2][1], 0, 0, 0);
            acc[3][0] = __builtin_amdgcn_mfma_f32_16x16x32_bf16(a3, b0, acc[3][0], 0, 0, 0);
            acc[3][1] = __builtin_amdgcn_mfma_f32_16x16x32_bf16(a3, b1, acc[3][1], 0, 0, 0);
        }
        __syncthreads();
    }

    // ---- epilogue: BN affine, store, per-channel partial sums ----
#pragma unroll
    for (int mt = 0; mt < 4; ++mt) {
#pragma unroll
        for (int r = 0; r < 4; ++r) {
            int m = mt * 16 + kg * 4 + r;
            float sc = scale_g[m], sh = shift_g[m];
            float v0 = acc[mt][0][r] * sc + sh;
            float v1 = acc[mt][1][r] * sc + sh;
            size_t orow = (size_t)(b * 64 + m) * HW + p0 + wid * 32 + ln;
            out[orow] = v0;
            out[orow + 16] = v1;
            float vs = v0 + v1;
            vs += __shfl_xor(vs, 1, 16);
            vs += __shfl_xor(vs, 2, 16);
            vs += __shfl_xor(vs, 4, 16);
            vs += __shfl_xor(vs, 8, 16);
            if (ln == 0) red[m * 4 + wid] = vs;
        }
    }
    __syncthreads();
    if (tid < 64)
        partial[tid * 1152 + tile] = red[tid * 4 + 0] + red[tid * 4 + 1] +
                                     red[tid * 4 + 2] + red[tid * 4 + 3];
}

// K3: pooled mean -> squeeze/excite MLP -> cw[b,c]; also emit cw-folded 7x7 weights
__global__ void ca_kernel(const float* __restrict__ partial,
                          const float* __restrict__ w1, const float* __restrict__ b1,
                          const float* __restrict__ w2, const float* __restrict__ b2,
                          const float* __restrict__ saw, float* __restrict__ cw,
                          float* __restrict__ we_eff) {
    __shared__ float pooled[256];
    __shared__ float t1[16];
    int t = threadIdx.x;
    int b = t >> 6, o = t & 63;
    const float* pr = partial + o * 1152 + b * 288;
    float s = 0.f;
#pragma unroll 8
    for (int q = 0; q < 72; ++q) {
        float4 v = ((const float4*)pr)[q];
        s += v.x + v.y + v.z + v.w;
    }
    pooled[t] = s * (1.0f / (float)HW);
    __syncthreads();
    if (t < 16) {
        int bb = t >> 2, hh = t & 3;
        float a = b1[hh];
        for (int c = 0; c < 64; ++c) a += pooled[bb * 64 + c] * w1[hh * 64 + c];
        t1[t] = fmaxf(a, 0.f);
    }
    __syncthreads();
    float a = b2[o];
#pragma unroll
    for (int h2 = 0; h2 < 4; ++h2) a += t1[b * 4 + h2] * w2[o * 4 + h2];
    float cwv = 1.f / (1.f + __expf(-a));
    cw[t] = cwv;
#pragma unroll
    for (int dy = 0; dy < 7; ++dy)
#pragma unroll
        for (int dx = 0; dx < 8; ++dx)
            we_eff[(t * 7 + dy) * 8 + dx] = (dx < 7) ? cwv * saw[o * 49 + dy * 7 + dx] : 0.f;
}

// K4: spatial attention 7x7 conv; weights via wave-uniform (scalar) loads.
__global__ __launch_bounds__(192) void sa_kernel(
    const float* __restrict__ h, const float* __restrict__ sab,
    const float* __restrict__ we_eff, float* __restrict__ sw) {
    int x = threadIdx.x, y = blockIdx.x, b = blockIdx.y;
    float acc = sab[0];
    for (int c = 0; c < 64; ++c) {
        const float* hb = h + (size_t)(b * 64 + c) * HW;
        const float* wb = we_eff + (b * 64 + c) * 56;
#pragma unroll
        for (int dy = 0; dy < 7; ++dy) {
            int yy = y + dy - 3;
            if (yy < 0 || yy >= H_) continue;
            const float* row = hb + yy * W_;
#pragma unroll
            for (int dx = 0; dx < 7; ++dx) {
                int xj = x + dx - 3;
                float v = (xj >= 0 && xj < W_) ? row[xj] : 0.f;
                acc += v * wb[dy * 8 + dx];
            }
        }
    }
    sw[(b * H_ + y) * W_ + x] = 1.f / (1.f + __expf(-acc));
}

// K5: out = h * cw[b,c] * sw[b,y,x]  (in-place on d_out)
__global__ void final_kernel(float* __restrict__ out, const float* __restrict__ cw,
                             const float* __restrict__ sw) {
    int idx = blockIdx.x * 256 + threadIdx.x;  // float4 index
    int e = idx * 4;
    int b = e / (64 * HW);
    int r = e % (64 * HW);
    int c = r / HW;
    int p = r % HW;
    float cwv = cw[b * 64 + c];
    float4 h4 = *(float4*)(out + e);
    float4 s4 = *(const float4*)(sw + b * HW + p);
    float4 o4;
    o4.x = h4.x * cwv * s4.x;
    o4.y = h4.y * cwv * s4.y;
    o4.z = h4.z * cwv * s4.z;
    o4.w = h4.w * cwv * s4.w;
    *(float4*)(out + e) = o4;
}

extern "C" void kernel_launch(void* const* d_in, const int* in_sizes, int n_in,
                              void* d_out, int out_size, void* d_ws, size_t ws_size,
                              hipStream_t stream) {
    const float* x     = (const float*)d_in[0];
    const float* off_w = (const float*)d_in[1];
    const float* off_b = (const float*)d_in[2];
    const float* dw    = (const float*)d_in[3];
    const float* db    = (const float*)d_in[4];
    const float* bn_g  = (const float*)d_in[5];
    const float* bn_b  = (const float*)d_in[6];
    const float* bn_m  = (const float*)d_in[7];
    const float* bn_v  = (const float*)d_in[8];
    const float* ca_w1 = (const float*)d_in[9];
    const float* ca_b1 = (const float*)d_in[10];
    const float* ca_w2 = (const float*)d_in[11];
    const float* ca_b2 = (const float*)d_in[12];
    const float* sa_w  = (const float*)d_in[13];
    const float* sa_b  = (const float*)d_in[14];
    float* out = (float*)d_out;
    float* ws  = (float*)d_ws;

    float* offset         = ws;
    unsigned short* w_bf  = (unsigned short*)(ws + 2654208);
    float* scale          = ws + 2672640;
    float* shift          = ws + 2672704;
    float* cw             = ws + 2672768;
    float* partial        = ws + 2673024;
    float* we_eff         = ws + 2746752;
    float* sw             = ws + 2761088;

    prep_kernel<<<144, 256, 0, stream>>>(dw, db, bn_g, bn_b, bn_m, bn_v, w_bf, scale, shift);
    offset_conv_kernel<<<dim3(192, 4), 192, 0, stream>>>(x, off_w, off_b, offset);
    deform_kernel<<<1152, 256, 0, stream>>>(x, offset, w_bf, scale, shift, out, partial);
    ca_kernel<<<1, 256, 0, stream>>>(partial, ca_w1, ca_b1, ca_w2, ca_b2, sa_w, cw, we_eff);
    sa_kernel<<<dim3(192, 4), 192, 0, stream>>>(out, sa_b, we_eff, sw);
    final_kernel<<<9216, 256, 0, stream>>>(out, cw, sw);
}

// Round 3
// 404.247 us; speedup vs baseline: 1.5343x; 1.4638x over previous
//
#include <hip/hip_runtime.h>

#define H_  192
#define W_  192
#define HW  36864
#define B_  4

typedef __attribute__((ext_vector_type(8))) short short8;
typedef __attribute__((ext_vector_type(4))) float f32x4;
typedef __attribute__((ext_vector_type(4))) unsigned int u32x4;
typedef unsigned short ushort_t;
typedef unsigned int uint_t;

__device__ __forceinline__ ushort_t f2bf(float v) {
    uint_t u = __builtin_bit_cast(uint_t, v);
    u += 0x7FFFu + ((u >> 16) & 1u);   // RNE
    return (ushort_t)(u >> 16);
}
__device__ __forceinline__ float bflo(uint_t u) {
    uint_t w = u << 16; return __builtin_bit_cast(float, w);
}
__device__ __forceinline__ float bfhi(uint_t u) {
    uint_t w = u & 0xFFFF0000u; return __builtin_bit_cast(float, w);
}
__device__ __forceinline__ short8 zero8() {
    u32x4 z = {0u, 0u, 0u, 0u};
    return __builtin_bit_cast(short8, z);
}

// ============ K0: weight prep ============
// w_bf [9][64][64] bf16 (deform), w_off [9][32][64] bf16 (offset conv, rows>=18 zero),
// scale/shift: BN+bias folded.
__global__ void prep_kernel(const float* __restrict__ dw, const float* __restrict__ db,
                            const float* __restrict__ g, const float* __restrict__ be,
                            const float* __restrict__ mu, const float* __restrict__ var,
                            const float* __restrict__ ow,
                            ushort_t* __restrict__ w_bf, ushort_t* __restrict__ w_off,
                            float* __restrict__ scale, float* __restrict__ shift) {
    int idx = blockIdx.x * 256 + threadIdx.x;
    if (idx < 36864) {
        int tap = idx >> 12, o = (idx >> 6) & 63, c = idx & 63;
        w_bf[idx] = f2bf(dw[(o * 64 + c) * 9 + tap]);
    }
    int idx2 = idx - 36864;
    if (idx2 >= 0 && idx2 < 18432) {
        int tap = idx2 >> 11, o = (idx2 >> 6) & 31, c = idx2 & 63;
        w_off[idx2] = (o < 18) ? f2bf(ow[(o * 64 + c) * 9 + tap]) : (ushort_t)0;
    }
    if (idx < 64) {
        float s = g[idx] * rsqrtf(var[idx] + 1e-5f);
        scale[idx] = s;
        shift[idx] = (db[idx] - mu[idx]) * s + be[idx];
    }
}

// ============ KT: x [B,C,HW] f32 -> x_t [B,HW,C] bf16 ============
__global__ __launch_bounds__(256) void transpose_kernel(const float* __restrict__ x,
                                                        ushort_t* __restrict__ x_t) {
    __shared__ uint_t tlds[256 * 33];   // rows of 66 shorts (pad 64->66)
    int tid = threadIdx.x;
    int b = blockIdx.x / 144;
    int p0 = (blockIdx.x % 144) * 256;
    ushort_t* ts = (ushort_t*)tlds;
    for (int c = 0; c < 64; ++c) {
        float v = x[((size_t)(b * 64 + c)) * HW + p0 + tid];
        ts[tid * 66 + c] = f2bf(v);
    }
    __syncthreads();
#pragma unroll
    for (int j = 0; j < 8; ++j) {
        int chunk = j * 256 + tid;
        int pl = chunk >> 3, s = chunk & 7;
        int bd = pl * 33 + s * 4;
        u32x4 v = {tlds[bd], tlds[bd + 1], tlds[bd + 2], tlds[bd + 3]};
        ((u32x4*)x_t)[(size_t)(b * HW + p0) * 8 + chunk] = v;
    }
}

// ============ helpers for fused deform ============
__device__ __forceinline__ void corner_setup(const float* off_lds, int ploc, int tap,
                                             int ybase, int xbase, int* idx, float* w) {
    float ody = off_lds[ploc * 19 + 2 * tap];
    float odx = off_lds[ploc * 19 + 2 * tap + 1];
    float py = (float)ybase + ody;
    float px = (float)xbase + odx;
    float fy = floorf(py), fx = floorf(px);
    int y0 = (int)fy, x0 = (int)fx;
    float wy = py - fy, wx = px - fx;
    int y0c = min(max(y0, 0), H_ - 1), y1c = min(max(y0 + 1, 0), H_ - 1);
    int x0c = min(max(x0, 0), W_ - 1), x1c = min(max(x0 + 1, 0), W_ - 1);
    float vy0 = (y0 >= 0 && y0 < H_) ? 1.f : 0.f;
    float vy1 = (y0 + 1 >= 0 && y0 + 1 < H_) ? 1.f : 0.f;
    float vx0 = (x0 >= 0 && x0 < W_) ? 1.f : 0.f;
    float vx1 = (x0 + 1 >= 0 && x0 + 1 < W_) ? 1.f : 0.f;
    w[0] = (1.f - wy) * (1.f - wx) * vy0 * vx0;
    w[1] = (1.f - wy) * wx * vy0 * vx1;
    w[2] = wy * (1.f - wx) * vy1 * vx0;
    w[3] = wy * wx * vy1 * vx1;
    idx[0] = (y0c * W_ + x0c) * 64; idx[1] = (y0c * W_ + x1c) * 64;
    idx[2] = (y1c * W_ + x0c) * 64; idx[3] = (y1c * W_ + x1c) * 64;
}

__device__ __forceinline__ short8 interp_frag(const ushort_t* base, const int* idx,
                                              const float* w) {
    u32x4 c0 = *(const u32x4*)(base + idx[0]);
    u32x4 c1 = *(const u32x4*)(base + idx[1]);
    u32x4 c2 = *(const u32x4*)(base + idx[2]);
    u32x4 c3 = *(const u32x4*)(base + idx[3]);
    short8 r;
#pragma unroll
    for (int q = 0; q < 4; ++q) {
        float lo = w[0] * bflo(c0[q]) + w[1] * bflo(c1[q]) + w[2] * bflo(c2[q]) + w[3] * bflo(c3[q]);
        float hi = w[0] * bfhi(c0[q]) + w[1] * bfhi(c1[q]) + w[2] * bfhi(c2[q]) + w[3] * bfhi(c3[q]);
        uint_t p = (uint_t)f2bf(lo) | ((uint_t)f2bf(hi) << 16);
        ((uint_t*)&r)[q] = p;
    }
    return r;
}

// ============ K2 (plan A): fused offset-conv + deformable conv, barrier-free MFMA ============
// Block: 128 positions, 4 waves; wave owns positions wid*32+ln (+16). No B-staging LDS.
__global__ __launch_bounds__(256) void deform_fused_kernel(
    const ushort_t* __restrict__ x_t, const ushort_t* __restrict__ w_off,
    const float* __restrict__ ob, const ushort_t* __restrict__ w_bf,
    const float* __restrict__ scale_g, const float* __restrict__ shift_g,
    float* __restrict__ out, float* __restrict__ partial) {
    __shared__ float off_lds[128 * 19];
    __shared__ float red[256];

    int tid = threadIdx.x;
    int tile = (blockIdx.x & 7) * 144 + (blockIdx.x >> 3);   // XCD-bijective (1152 % 8 == 0)
    int b = tile / 288;
    int p0 = (tile % 288) * 128;

    int wid = tid >> 6, lane = tid & 63, ln = lane & 15, kg = lane >> 4;
    int pA_loc = wid * 32 + ln, pB_loc = pA_loc + 16;
    int pA = p0 + pA_loc, pB = p0 + pB_loc;
    int yA = pA / 192, xA = pA - yA * 192;
    int yB = pB / 192, xB = pB - yB * 192;
    const ushort_t* xt_b = x_t + (size_t)b * (HW * 64);

    // ---- phase 0: offset conv (M=32, rows 0..17 used), direct bf16 B loads ----
    f32x4 ao[2][2];
#pragma unroll
    for (int i = 0; i < 2; ++i)
#pragma unroll
        for (int j = 0; j < 2; ++j) ao[i][j] = (f32x4){0.f, 0.f, 0.f, 0.f};

    for (int tap = 0; tap < 9; ++tap) {
        int ti = tap / 3 - 1, tj = tap % 3 - 1;
        short8 bA[2], bB[2];
        {
            int yy = yA + ti, xx = xA + tj;
            bool v = (yy >= 0 && yy < H_ && xx >= 0 && xx < W_);
            int base = (min(max(yy, 0), H_ - 1) * W_ + min(max(xx, 0), W_ - 1)) * 64;
#pragma unroll
            for (int ks = 0; ks < 2; ++ks) {
                short8 t8 = *(const short8*)(xt_b + base + ks * 32 + kg * 8);
                bA[ks] = v ? t8 : zero8();
            }
        }
        {
            int yy = yB + ti, xx = xB + tj;
            bool v = (yy >= 0 && yy < H_ && xx >= 0 && xx < W_);
            int base = (min(max(yy, 0), H_ - 1) * W_ + min(max(xx, 0), W_ - 1)) * 64;
#pragma unroll
            for (int ks = 0; ks < 2; ++ks) {
                short8 t8 = *(const short8*)(xt_b + base + ks * 32 + kg * 8);
                bB[ks] = v ? t8 : zero8();
            }
        }
        const ushort_t* wt = w_off + tap * 2048;
#pragma unroll
        for (int ks = 0; ks < 2; ++ks) {
            int ch = ks * 32 + kg * 8;
            short8 a0 = *(const short8*)(wt + ln * 64 + ch);
            short8 a1 = *(const short8*)(wt + (16 + ln) * 64 + ch);
            ao[0][0] = __builtin_amdgcn_mfma_f32_16x16x32_bf16(a0, bA[ks], ao[0][0], 0, 0, 0);
            ao[0][1] = __builtin_amdgcn_mfma_f32_16x16x32_bf16(a0, bB[ks], ao[0][1], 0, 0, 0);
            ao[1][0] = __builtin_amdgcn_mfma_f32_16x16x32_bf16(a1, bA[ks], ao[1][0], 0, 0, 0);
            ao[1][1] = __builtin_amdgcn_mfma_f32_16x16x32_bf16(a1, bB[ks], ao[1][1], 0, 0, 0);
        }
    }
    // distribute the 18 offset channels to LDS (pad 19 for banks)
#pragma unroll
    for (int mt = 0; mt < 2; ++mt)
#pragma unroll
        for (int r = 0; r < 4; ++r) {
            int m = mt * 16 + kg * 4 + r;
            if (m < 18) {
                float bias = ob[m];
                off_lds[pA_loc * 19 + m] = ao[mt][0][r] + bias;
                off_lds[pB_loc * 19 + m] = ao[mt][1][r] + bias;
            }
        }
    __syncthreads();

    // ---- main: deformable conv, per-lane direct fragment gather ----
    f32x4 acc[4][2];
#pragma unroll
    for (int mt = 0; mt < 4; ++mt)
#pragma unroll
        for (int nt = 0; nt < 2; ++nt) acc[mt][nt] = (f32x4){0.f, 0.f, 0.f, 0.f};

    for (int tap = 0; tap < 9; ++tap) {
        int ti = tap / 3 - 1, tj = tap % 3 - 1;
        int iA[4], iB[4];
        float wA[4], wB[4];
        corner_setup(off_lds, pA_loc, tap, yA + ti, xA + tj, iA, wA);
        corner_setup(off_lds, pB_loc, tap, yB + ti, xB + tj, iB, wB);
        const ushort_t* wt = w_bf + tap * 4096;
#pragma unroll
        for (int ks = 0; ks < 2; ++ks) {
            int ch = ks * 32 + kg * 8;
            short8 fA = interp_frag(xt_b + ch, iA, wA);
            short8 fB = interp_frag(xt_b + ch, iB, wB);
            short8 a0 = *(const short8*)(wt + (0 + ln) * 64 + ch);
            short8 a1 = *(const short8*)(wt + (16 + ln) * 64 + ch);
            short8 a2 = *(const short8*)(wt + (32 + ln) * 64 + ch);
            short8 a3 = *(const short8*)(wt + (48 + ln) * 64 + ch);
            acc[0][0] = __builtin_amdgcn_mfma_f32_16x16x32_bf16(a0, fA, acc[0][0], 0, 0, 0);
            acc[0][1] = __builtin_amdgcn_mfma_f32_16x16x32_bf16(a0, fB, acc[0][1], 0, 0, 0);
            acc[1][0] = __builtin_amdgcn_mfma_f32_16x16x32_bf16(a1, fA, acc[1][0], 0, 0, 0);
            acc[1][1] = __builtin_amdgcn_mfma_f32_16x16x32_bf16(a1, fB, acc[1][1], 0, 0, 0);
            acc[2][0] = __builtin_amdgcn_mfma_f32_16x16x32_bf16(a2, fA, acc[2][0], 0, 0, 0);
            acc[2][1] = __builtin_amdgcn_mfma_f32_16x16x32_bf16(a2, fB, acc[2][1], 0, 0, 0);
            acc[3][0] = __builtin_amdgcn_mfma_f32_16x16x32_bf16(a3, fA, acc[3][0], 0, 0, 0);
            acc[3][1] = __builtin_amdgcn_mfma_f32_16x16x32_bf16(a3, fB, acc[3][1], 0, 0, 0);
        }
    }

    // ---- epilogue: BN affine, store, per-channel partial sums ----
#pragma unroll
    for (int mt = 0; mt < 4; ++mt) {
#pragma unroll
        for (int r = 0; r < 4; ++r) {
            int m = mt * 16 + kg * 4 + r;
            float sc = scale_g[m], sh = shift_g[m];
            float v0 = acc[mt][0][r] * sc + sh;
            float v1 = acc[mt][1][r] * sc + sh;
            size_t orow = (size_t)(b * 64 + m) * HW + p0 + wid * 32 + ln;
            out[orow] = v0;
            out[orow + 16] = v1;
            float vs = v0 + v1;
            vs += __shfl_xor(vs, 1, 16);
            vs += __shfl_xor(vs, 2, 16);
            vs += __shfl_xor(vs, 4, 16);
            vs += __shfl_xor(vs, 8, 16);
            if (ln == 0) red[m * 4 + wid] = vs;
        }
    }
    __syncthreads();
    if (tid < 64)
        partial[tid * 1152 + tile] = red[tid * 4 + 0] + red[tid * 4 + 1] +
                                     red[tid * 4 + 2] + red[tid * 4 + 3];
}

// ============ plan-B kernels (round-2, used only if ws is small) ============
__global__ __launch_bounds__(192) void offset_conv_kernel(
    const float* __restrict__ x, const float* __restrict__ ow,
    const float* __restrict__ ob, float* __restrict__ offset) {
    int xx = threadIdx.x;
    int y = blockIdx.x;
    int b = blockIdx.y;
    float acc[18];
#pragma unroll
    for (int oc = 0; oc < 18; ++oc) acc[oc] = ob[oc];
    for (int c = 0; c < 64; ++c) {
        const float* xc = x + (size_t)(b * 64 + c) * HW;
#pragma unroll
        for (int i = 0; i < 3; ++i) {
            int yy = y + i - 1;
            if (yy < 0 || yy >= H_) continue;
            const float* row = xc + yy * W_;
#pragma unroll
            for (int j = 0; j < 3; ++j) {
                int xj = xx + j - 1;
                float v = (xj >= 0 && xj < W_) ? row[xj] : 0.0f;
#pragma unroll
                for (int oc = 0; oc < 18; ++oc)
                    acc[oc] += v * ow[(oc * 64 + c) * 9 + i * 3 + j];
            }
        }
    }
#pragma unroll
    for (int oc = 0; oc < 18; ++oc)
        offset[((b * 18 + oc) * H_ + y) * W_ + xx] = acc[oc];
}

__global__ __launch_bounds__(256) void deform_kernel_v2(
    const float* __restrict__ x, const float* __restrict__ offset,
    const ushort_t* __restrict__ w_bf, const float* __restrict__ scale_g,
    const float* __restrict__ shift_g, float* __restrict__ out,
    float* __restrict__ partial) {
    __shared__ __align__(16) ushort_t s_lds[8192];
    __shared__ float red[256];
    int tid = threadIdx.x;
    int tile = (blockIdx.x & 7) * 144 + (blockIdx.x >> 3);
    int b = tile / 288;
    int p0 = (tile % 288) * 128;
    int n_loc = tid & 127;
    int ch0 = (tid >> 7) * 32;
    int p = p0 + n_loc;
    int y = p / 192;
    int xx = p - y * 192;
    int wid = tid >> 6, lane = tid & 63, ln = lane & 15, kg = lane >> 4;
    f32x4 acc[4][2];
#pragma unroll
    for (int mt = 0; mt < 4; ++mt)
#pragma unroll
        for (int nt = 0; nt < 2; ++nt) acc[mt][nt] = (f32x4){0.f, 0.f, 0.f, 0.f};
    const float* xb = x + (size_t)(b * 64 + ch0) * HW;
    for (int tap = 0; tap < 9; ++tap) {
        int ti = tap / 3, tj = tap % 3;
        {
            float ody = offset[(size_t)(b * 18 + 2 * tap) * HW + p];
            float odx = offset[(size_t)(b * 18 + 2 * tap + 1) * HW + p];
            float py = (float)(y + ti - 1) + ody;
            float px = (float)(xx + tj - 1) + odx;
            float fy = floorf(py), fx = floorf(px);
            int y0 = (int)fy, x0i = (int)fx;
            float wy = py - fy, wx = px - fx;
            int y0c = min(max(y0, 0), H_ - 1), y1c = min(max(y0 + 1, 0), H_ - 1);
            int x0c = min(max(x0i, 0), W_ - 1), x1c = min(max(x0i + 1, 0), W_ - 1);
            float vy0 = (y0 >= 0 && y0 < H_) ? 1.f : 0.f;
            float vy1 = (y0 + 1 >= 0 && y0 + 1 < H_) ? 1.f : 0.f;
            float vx0 = (x0i >= 0 && x0i < W_) ? 1.f : 0.f;
            float vx1 = (x0i + 1 >= 0 && x0i + 1 < W_) ? 1.f : 0.f;
            float w00 = (1.f - wy) * (1.f - wx) * vy0 * vx0;
            float w01 = (1.f - wy) * wx * vy0 * vx1;
            float w10 = wy * (1.f - wx) * vy1 * vx0;
            float w11 = wy * wx * vy1 * vx1;
            int i00 = y0c * W_ + x0c, i01 = y0c * W_ + x1c;
            int i10 = y1c * W_ + x0c, i11 = y1c * W_ + x1c;
#pragma unroll
            for (int cb = 0; cb < 4; ++cb) {
                short8 v8;
#pragma unroll
                for (int q = 0; q < 8; ++q) {
                    const float* xc = xb + (size_t)(cb * 8 + q) * HW;
                    float v = w00 * xc[i00] + w01 * xc[i01] + w10 * xc[i10] + w11 * xc[i11];
                    v8[q] = (short)f2bf(v);
                }
                int slot = (ch0 >> 3) + cb;
                int addr = n_loc * 128 + ((slot * 16) ^ ((n_loc & 7) << 4));
                *(short8*)((char*)s_lds + addr) = v8;
            }
        }
        __syncthreads();
        const ushort_t* wtap = w_bf + tap * 4096;
#pragma unroll
        for (int ks = 0; ks < 2; ++ks) {
            short8 a0 = *(const short8*)(wtap + (0 + ln) * 64 + ks * 32 + kg * 8);
            short8 a1 = *(const short8*)(wtap + (16 + ln) * 64 + ks * 32 + kg * 8);
            short8 a2 = *(const short8*)(wtap + (32 + ln) * 64 + ks * 32 + kg * 8);
            short8 a3 = *(const short8*)(wtap + (48 + ln) * 64 + ks * 32 + kg * 8);
            int cslot = ks * 4 + kg;
            int n0g = wid * 32 + ln;
            int n1g = n0g + 16;
            short8 b0 = *(const short8*)((char*)s_lds + n0g * 128 + ((cslot * 16) ^ ((n0g & 7) << 4)));
            short8 b1 = *(const short8*)((char*)s_lds + n1g * 128 + ((cslot * 16) ^ ((n1g & 7) << 4)));
            acc[0][0] = __builtin_amdgcn_mfma_f32_16x16x32_bf16(a0, b0, acc[0][0], 0, 0, 0);
            acc[0][1] = __builtin_amdgcn_mfma_f32_16x16x32_bf16(a0, b1, acc[0][1], 0, 0, 0);
            acc[1][0] = __builtin_amdgcn_mfma_f32_16x16x32_bf16(a1, b0, acc[1][0], 0, 0, 0);
            acc[1][1] = __builtin_amdgcn_mfma_f32_16x16x32_bf16(a1, b1, acc[1][1], 0, 0, 0);
            acc[2][0] = __builtin_amdgcn_mfma_f32_16x16x32_bf16(a2, b0, acc[2][0], 0, 0, 0);
            acc[2][1] = __builtin_amdgcn_mfma_f32_16x16x32_bf16(a2, b1, acc[2][1], 0, 0, 0);
            acc[3][0] = __builtin_amdgcn_mfma_f32_16x16x32_bf16(a3, b0, acc[3][0], 0, 0, 0);
            acc[3][1] = __builtin_amdgcn_mfma_f32_16x16x32_bf16(a3, b1, acc[3][1], 0, 0, 0);
        }
        __syncthreads();
    }
#pragma unroll
    for (int mt = 0; mt < 4; ++mt) {
#pragma unroll
        for (int r = 0; r < 4; ++r) {
            int m = mt * 16 + kg * 4 + r;
            float sc = scale_g[m], sh = shift_g[m];
            float v0 = acc[mt][0][r] * sc + sh;
            float v1 = acc[mt][1][r] * sc + sh;
            size_t orow = (size_t)(b * 64 + m) * HW + p0 + wid * 32 + ln;
            out[orow] = v0;
            out[orow + 16] = v1;
            float vs = v0 + v1;
            vs += __shfl_xor(vs, 1, 16);
            vs += __shfl_xor(vs, 2, 16);
            vs += __shfl_xor(vs, 4, 16);
            vs += __shfl_xor(vs, 8, 16);
            if (ln == 0) red[m * 4 + wid] = vs;
        }
    }
    __syncthreads();
    if (tid < 64)
        partial[tid * 1152 + tile] = red[tid * 4 + 0] + red[tid * 4 + 1] +
                                     red[tid * 4 + 2] + red[tid * 4 + 3];
}

// ============ KR: parallel partial reduce -> pooled mean ============
__global__ void reduce_kernel(const float* __restrict__ partial, float* __restrict__ pooled) {
    int o = blockIdx.x & 63, b = blockIdx.x >> 6;
    const float* pr = partial + o * 1152 + b * 288;
    int t = threadIdx.x;
    float s = 0.f;
    for (int q = t; q < 288; q += 64) s += pr[q];
#pragma unroll
    for (int d = 1; d < 64; d <<= 1) s += __shfl_xor(s, d, 64);
    if (t == 0) pooled[b * 64 + o] = s * (1.0f / (float)HW);
}

// ============ K3: squeeze/excite MLP -> cw; cw-folded 7x7 weights ============
__global__ void ca_kernel(const float* __restrict__ pooled_g,
                          const float* __restrict__ w1, const float* __restrict__ b1,
                          const float* __restrict__ w2, const float* __restrict__ b2,
                          const float* __restrict__ saw, float* __restrict__ cw,
                          float* __restrict__ we_eff) {
    __shared__ float pooled[256];
    __shared__ float t1[16];
    int t = threadIdx.x;
    int b = t >> 6, o = t & 63;
    pooled[t] = pooled_g[t];
    __syncthreads();
    if (t < 16) {
        int bb = t >> 2, hh = t & 3;
        float a = b1[hh];
        for (int c = 0; c < 64; ++c) a += pooled[bb * 64 + c] * w1[hh * 64 + c];
        t1[t] = fmaxf(a, 0.f);
    }
    __syncthreads();
    float a = b2[o];
#pragma unroll
    for (int h2 = 0; h2 < 4; ++h2) a += t1[b * 4 + h2] * w2[o * 4 + h2];
    float cwv = 1.f / (1.f + __expf(-a));
    cw[t] = cwv;
#pragma unroll
    for (int dy = 0; dy < 7; ++dy)
#pragma unroll
        for (int dx = 0; dx < 8; ++dx)
            we_eff[(t * 7 + dy) * 8 + dx] = (dx < 7) ? cwv * saw[o * 49 + dy * 7 + dx] : 0.f;
}

// ============ K4: spatial attention 7x7 ============
__global__ __launch_bounds__(192) void sa_kernel(
    const float* __restrict__ h, const float* __restrict__ sab,
    const float* __restrict__ we_eff, float* __restrict__ sw) {
    int x = threadIdx.x, y = blockIdx.x, b = blockIdx.y;
    float acc = sab[0];
    for (int c = 0; c < 64; ++c) {
        const float* hb = h + (size_t)(b * 64 + c) * HW;
        const float* wb = we_eff + (b * 64 + c) * 56;
#pragma unroll
        for (int dy = 0; dy < 7; ++dy) {
            int yy = y + dy - 3;
            if (yy < 0 || yy >= H_) continue;
            const float* row = hb + yy * W_;
#pragma unroll
            for (int dx = 0; dx < 7; ++dx) {
                int xj = x + dx - 3;
                float v = (xj >= 0 && xj < W_) ? row[xj] : 0.f;
                acc += v * wb[dy * 8 + dx];
            }
        }
    }
    sw[(b * H_ + y) * W_ + x] = 1.f / (1.f + __expf(-acc));
}

// ============ K5: out = h * cw * sw ============
__global__ void final_kernel(float* __restrict__ out, const float* __restrict__ cw,
                             const float* __restrict__ sw) {
    int idx = blockIdx.x * 256 + threadIdx.x;
    int e = idx * 4;
    int b = e / (64 * HW);
    int r = e % (64 * HW);
    int c = r / HW;
    int p = r % HW;
    float cwv = cw[b * 64 + c];
    float4 h4 = *(float4*)(out + e);
    float4 s4 = *(const float4*)(sw + b * HW + p);
    float4 o4;
    o4.x = h4.x * cwv * s4.x;
    o4.y = h4.y * cwv * s4.y;
    o4.z = h4.z * cwv * s4.z;
    o4.w = h4.w * cwv * s4.w;
    *(float4*)(out + e) = o4;
}

extern "C" void kernel_launch(void* const* d_in, const int* in_sizes, int n_in,
                              void* d_out, int out_size, void* d_ws, size_t ws_size,
                              hipStream_t stream) {
    const float* x     = (const float*)d_in[0];
    const float* off_w = (const float*)d_in[1];
    const float* off_b = (const float*)d_in[2];
    const float* dw    = (const float*)d_in[3];
    const float* db    = (const float*)d_in[4];
    const float* bn_g  = (const float*)d_in[5];
    const float* bn_b  = (const float*)d_in[6];
    const float* bn_m  = (const float*)d_in[7];
    const float* bn_v  = (const float*)d_in[8];
    const float* ca_w1 = (const float*)d_in[9];
    const float* ca_b1 = (const float*)d_in[10];
    const float* ca_w2 = (const float*)d_in[11];
    const float* ca_b2 = (const float*)d_in[12];
    const float* sa_w  = (const float*)d_in[13];
    const float* sa_b  = (const float*)d_in[14];
    float* out = (float*)d_out;
    float* ws  = (float*)d_ws;

    const size_t NEED_A = 4982400ull * 4ull;   // 19.93 MB

    if (ws_size >= NEED_A) {
        // ---- plan A: NHWC bf16 + fused offset/deform ----
        ushort_t* x_t    = (ushort_t*)ws;                      // 9437184 shorts
        ushort_t* w_bf   = (ushort_t*)(ws + 4718592);
        ushort_t* w_off  = (ushort_t*)(ws + 4737024);
        float* scale     = ws + 4746240;
        float* shift     = ws + 4746304;
        float* cw        = ws + 4746368;
        float* pooled    = ws + 4746624;
        float* partial   = ws + 4746880;
        float* we_eff    = ws + 4820608;
        float* sw        = ws + 4834944;

        prep_kernel<<<216, 256, 0, stream>>>(dw, db, bn_g, bn_b, bn_m, bn_v, off_w,
                                             w_bf, w_off, scale, shift);
        transpose_kernel<<<576, 256, 0, stream>>>(x, x_t);
        deform_fused_kernel<<<1152, 256, 0, stream>>>(x_t, w_off, off_b, w_bf,
                                                      scale, shift, out, partial);
        reduce_kernel<<<256, 64, 0, stream>>>(partial, pooled);
        ca_kernel<<<1, 256, 0, stream>>>(pooled, ca_w1, ca_b1, ca_w2, ca_b2, sa_w, cw, we_eff);
        sa_kernel<<<dim3(192, 4), 192, 0, stream>>>(out, sa_b, we_eff, sw);
        final_kernel<<<9216, 256, 0, stream>>>(out, cw, sw);
    } else {
        // ---- plan B: round-2 pipeline (fits in 11.64 MB) ----
        float* offset    = ws;
        ushort_t* w_bf   = (ushort_t*)(ws + 2654208);
        float* scale     = ws + 2672640;
        float* shift     = ws + 2672704;
        float* cw        = ws + 2672768;
        float* pooled    = ws + 2673024;
        float* partial   = ws + 2673280;
        float* we_eff    = ws + 2747008;
        float* sw        = ws + 2761344;
        ushort_t* w_off  = (ushort_t*)partial;   // scratch; overwritten by deform later

        prep_kernel<<<216, 256, 0, stream>>>(dw, db, bn_g, bn_b, bn_m, bn_v, off_w,
                                             w_bf, w_off, scale, shift);
        offset_conv_kernel<<<dim3(192, 4), 192, 0, stream>>>(x, off_w, off_b, offset);
        deform_kernel_v2<<<1152, 256, 0, stream>>>(x, offset, w_bf, scale, shift, out, partial);
        reduce_kernel<<<256, 64, 0, stream>>>(partial, pooled);
        ca_kernel<<<1, 256, 0, stream>>>(pooled, ca_w1, ca_b1, ca_w2, ca_b2, sa_w, cw, we_eff);
        sa_kernel<<<dim3(192, 4), 192, 0, stream>>>(out, sa_b, we_eff, sw);
        final_kernel<<<9216, 256, 0, stream>>>(out, cw, sw);
    }
}

// Round 4
// 231.158 us; speedup vs baseline: 2.6832x; 1.7488x over previous
//
#include <hip/hip_runtime.h>

#define H_  192
#define W_  192
#define HW  36864
#define B_  4

typedef __attribute__((ext_vector_type(8))) short short8;
typedef __attribute__((ext_vector_type(4))) float f32x4;
typedef __attribute__((ext_vector_type(4))) unsigned int u32x4;
typedef unsigned short ushort_t;
typedef unsigned int uint_t;

__device__ __forceinline__ ushort_t f2bf(float v) {
    uint_t u = __builtin_bit_cast(uint_t, v);
    u += 0x7FFFu + ((u >> 16) & 1u);   // RNE
    return (ushort_t)(u >> 16);
}
__device__ __forceinline__ float bflo(uint_t u) {
    uint_t w = u << 16; return __builtin_bit_cast(float, w);
}
__device__ __forceinline__ float bfhi(uint_t u) {
    uint_t w = u & 0xFFFF0000u; return __builtin_bit_cast(float, w);
}
__device__ __forceinline__ short8 zero8() {
    u32x4 z = {0u, 0u, 0u, 0u};
    return __builtin_bit_cast(short8, z);
}

// ============ K0: weight prep ============
__global__ void prep_kernel(const float* __restrict__ dw, const float* __restrict__ db,
                            const float* __restrict__ g, const float* __restrict__ be,
                            const float* __restrict__ mu, const float* __restrict__ var,
                            const float* __restrict__ ow,
                            ushort_t* __restrict__ w_bf, ushort_t* __restrict__ w_off,
                            float* __restrict__ scale, float* __restrict__ shift) {
    int idx = blockIdx.x * 256 + threadIdx.x;
    if (idx < 36864) {
        int tap = idx >> 12, o = (idx >> 6) & 63, c = idx & 63;
        w_bf[idx] = f2bf(dw[(o * 64 + c) * 9 + tap]);
    }
    int idx2 = idx - 36864;
    if (idx2 >= 0 && idx2 < 18432) {
        int tap = idx2 >> 11, o = (idx2 >> 6) & 31, c = idx2 & 63;
        w_off[idx2] = (o < 18) ? f2bf(ow[(o * 64 + c) * 9 + tap]) : (ushort_t)0;
    }
    if (idx < 64) {
        float s = g[idx] * rsqrtf(var[idx] + 1e-5f);
        scale[idx] = s;
        shift[idx] = (db[idx] - mu[idx]) * s + be[idx];
    }
}

// ============ KT: x [B,C,HW] f32 -> x_t [B,HW,C] bf16 ============
__global__ __launch_bounds__(256) void transpose_kernel(const float* __restrict__ x,
                                                        ushort_t* __restrict__ x_t) {
    __shared__ uint_t tlds[256 * 33];
    int tid = threadIdx.x;
    int b = blockIdx.x / 144;
    int p0 = (blockIdx.x % 144) * 256;
    ushort_t* ts = (ushort_t*)tlds;
    for (int c = 0; c < 64; ++c) {
        float v = x[((size_t)(b * 64 + c)) * HW + p0 + tid];
        ts[tid * 66 + c] = f2bf(v);
    }
    __syncthreads();
#pragma unroll
    for (int j = 0; j < 8; ++j) {
        int chunk = j * 256 + tid;
        int pl = chunk >> 3, s = chunk & 7;
        int bd = pl * 33 + s * 4;
        u32x4 v = {tlds[bd], tlds[bd + 1], tlds[bd + 2], tlds[bd + 3]};
        ((u32x4*)x_t)[(size_t)(b * HW + p0) * 8 + chunk] = v;
    }
}

// ============ helpers for fused deform ============
__device__ __forceinline__ void corner_setup(const float* off_lds, int ploc, int tap,
                                             int ybase, int xbase, int* idx, float* w) {
    float ody = off_lds[ploc * 19 + 2 * tap];
    float odx = off_lds[ploc * 19 + 2 * tap + 1];
    float py = (float)ybase + ody;
    float px = (float)xbase + odx;
    float fy = floorf(py), fx = floorf(px);
    int y0 = (int)fy, x0 = (int)fx;
    float wy = py - fy, wx = px - fx;
    int y0c = min(max(y0, 0), H_ - 1), y1c = min(max(y0 + 1, 0), H_ - 1);
    int x0c = min(max(x0, 0), W_ - 1), x1c = min(max(x0 + 1, 0), W_ - 1);
    float vy0 = (y0 >= 0 && y0 < H_) ? 1.f : 0.f;
    float vy1 = (y0 + 1 >= 0 && y0 + 1 < H_) ? 1.f : 0.f;
    float vx0 = (x0 >= 0 && x0 < W_) ? 1.f : 0.f;
    float vx1 = (x0 + 1 >= 0 && x0 + 1 < W_) ? 1.f : 0.f;
    w[0] = (1.f - wy) * (1.f - wx) * vy0 * vx0;
    w[1] = (1.f - wy) * wx * vy0 * vx1;
    w[2] = wy * (1.f - wx) * vy1 * vx0;
    w[3] = wy * wx * vy1 * vx1;
    idx[0] = (y0c * W_ + x0c) * 64; idx[1] = (y0c * W_ + x1c) * 64;
    idx[2] = (y1c * W_ + x0c) * 64; idx[3] = (y1c * W_ + x1c) * 64;
}

__device__ __forceinline__ short8 interp_frag(const ushort_t* base, const int* idx,
                                              const float* w) {
    u32x4 c0 = *(const u32x4*)(base + idx[0]);
    u32x4 c1 = *(const u32x4*)(base + idx[1]);
    u32x4 c2 = *(const u32x4*)(base + idx[2]);
    u32x4 c3 = *(const u32x4*)(base + idx[3]);
    short8 r;
#pragma unroll
    for (int q = 0; q < 4; ++q) {
        float lo = w[0] * bflo(c0[q]) + w[1] * bflo(c1[q]) + w[2] * bflo(c2[q]) + w[3] * bflo(c3[q]);
        float hi = w[0] * bfhi(c0[q]) + w[1] * bfhi(c1[q]) + w[2] * bfhi(c2[q]) + w[3] * bfhi(c3[q]);
        uint_t p = (uint_t)f2bf(lo) | ((uint_t)f2bf(hi) << 16);
        ((uint_t*)&r)[q] = p;
    }
    return r;
}

// ============ K2: fused offset-conv + deformable conv ============
__global__ __launch_bounds__(256) void deform_fused_kernel(
    const ushort_t* __restrict__ x_t, const ushort_t* __restrict__ w_off,
    const float* __restrict__ ob, const ushort_t* __restrict__ w_bf,
    const float* __restrict__ scale_g, const float* __restrict__ shift_g,
    float* __restrict__ out, float* __restrict__ partial) {
    __shared__ float off_lds[128 * 19];
    __shared__ float red[256];

    int tid = threadIdx.x;
    int tile = (blockIdx.x & 7) * 144 + (blockIdx.x >> 3);   // XCD-bijective
    int b = tile / 288;
    int p0 = (tile % 288) * 128;

    int wid = tid >> 6, lane = tid & 63, ln = lane & 15, kg = lane >> 4;
    int pA_loc = wid * 32 + ln, pB_loc = pA_loc + 16;
    int pA = p0 + pA_loc, pB = p0 + pB_loc;
    int yA = pA / 192, xA = pA - yA * 192;
    int yB = pB / 192, xB = pB - yB * 192;
    const ushort_t* xt_b = x_t + (size_t)b * (HW * 64);

    // ---- phase 0: offset conv ----
    f32x4 ao[2][2];
#pragma unroll
    for (int i = 0; i < 2; ++i)
#pragma unroll
        for (int j = 0; j < 2; ++j) ao[i][j] = (f32x4){0.f, 0.f, 0.f, 0.f};

    for (int tap = 0; tap < 9; ++tap) {
        int ti = tap / 3 - 1, tj = tap % 3 - 1;
        short8 bA[2], bB[2];
        {
            int yy = yA + ti, xx = xA + tj;
            bool v = (yy >= 0 && yy < H_ && xx >= 0 && xx < W_);
            int base = (min(max(yy, 0), H_ - 1) * W_ + min(max(xx, 0), W_ - 1)) * 64;
#pragma unroll
            for (int ks = 0; ks < 2; ++ks) {
                short8 t8 = *(const short8*)(xt_b + base + ks * 32 + kg * 8);
                bA[ks] = v ? t8 : zero8();
            }
        }
        {
            int yy = yB + ti, xx = xB + tj;
            bool v = (yy >= 0 && yy < H_ && xx >= 0 && xx < W_);
            int base = (min(max(yy, 0), H_ - 1) * W_ + min(max(xx, 0), W_ - 1)) * 64;
#pragma unroll
            for (int ks = 0; ks < 2; ++ks) {
                short8 t8 = *(const short8*)(xt_b + base + ks * 32 + kg * 8);
                bB[ks] = v ? t8 : zero8();
            }
        }
        const ushort_t* wt = w_off + tap * 2048;
#pragma unroll
        for (int ks = 0; ks < 2; ++ks) {
            int ch = ks * 32 + kg * 8;
            short8 a0 = *(const short8*)(wt + ln * 64 + ch);
            short8 a1 = *(const short8*)(wt + (16 + ln) * 64 + ch);
            ao[0][0] = __builtin_amdgcn_mfma_f32_16x16x32_bf16(a0, bA[ks], ao[0][0], 0, 0, 0);
            ao[0][1] = __builtin_amdgcn_mfma_f32_16x16x32_bf16(a0, bB[ks], ao[0][1], 0, 0, 0);
            ao[1][0] = __builtin_amdgcn_mfma_f32_16x16x32_bf16(a1, bA[ks], ao[1][0], 0, 0, 0);
            ao[1][1] = __builtin_amdgcn_mfma_f32_16x16x32_bf16(a1, bB[ks], ao[1][1], 0, 0, 0);
        }
    }
#pragma unroll
    for (int mt = 0; mt < 2; ++mt)
#pragma unroll
        for (int r = 0; r < 4; ++r) {
            int m = mt * 16 + kg * 4 + r;
            if (m < 18) {
                float bias = ob[m];
                off_lds[pA_loc * 19 + m] = ao[mt][0][r] + bias;
                off_lds[pB_loc * 19 + m] = ao[mt][1][r] + bias;
            }
        }
    __syncthreads();

    // ---- main: deformable conv ----
    f32x4 acc[4][2];
#pragma unroll
    for (int mt = 0; mt < 4; ++mt)
#pragma unroll
        for (int nt = 0; nt < 2; ++nt) acc[mt][nt] = (f32x4){0.f, 0.f, 0.f, 0.f};

    for (int tap = 0; tap < 9; ++tap) {
        int ti = tap / 3 - 1, tj = tap % 3 - 1;
        int iA[4], iB[4];
        float wA[4], wB[4];
        corner_setup(off_lds, pA_loc, tap, yA + ti, xA + tj, iA, wA);
        corner_setup(off_lds, pB_loc, tap, yB + ti, xB + tj, iB, wB);
        const ushort_t* wt = w_bf + tap * 4096;
#pragma unroll
        for (int ks = 0; ks < 2; ++ks) {
            int ch = ks * 32 + kg * 8;
            short8 fA = interp_frag(xt_b + ch, iA, wA);
            short8 fB = interp_frag(xt_b + ch, iB, wB);
            short8 a0 = *(const short8*)(wt + (0 + ln) * 64 + ch);
            short8 a1 = *(const short8*)(wt + (16 + ln) * 64 + ch);
            short8 a2 = *(const short8*)(wt + (32 + ln) * 64 + ch);
            short8 a3 = *(const short8*)(wt + (48 + ln) * 64 + ch);
            acc[0][0] = __builtin_amdgcn_mfma_f32_16x16x32_bf16(a0, fA, acc[0][0], 0, 0, 0);
            acc[0][1] = __builtin_amdgcn_mfma_f32_16x16x32_bf16(a0, fB, acc[0][1], 0, 0, 0);
            acc[1][0] = __builtin_amdgcn_mfma_f32_16x16x32_bf16(a1, fA, acc[1][0], 0, 0, 0);
            acc[1][1] = __builtin_amdgcn_mfma_f32_16x16x32_bf16(a1, fB, acc[1][1], 0, 0, 0);
            acc[2][0] = __builtin_amdgcn_mfma_f32_16x16x32_bf16(a2, fA, acc[2][0], 0, 0, 0);
            acc[2][1] = __builtin_amdgcn_mfma_f32_16x16x32_bf16(a2, fB, acc[2][1], 0, 0, 0);
            acc[3][0] = __builtin_amdgcn_mfma_f32_16x16x32_bf16(a3, fA, acc[3][0], 0, 0, 0);
            acc[3][1] = __builtin_amdgcn_mfma_f32_16x16x32_bf16(a3, fB, acc[3][1], 0, 0, 0);
        }
    }

    // ---- epilogue ----
#pragma unroll
    for (int mt = 0; mt < 4; ++mt) {
#pragma unroll
        for (int r = 0; r < 4; ++r) {
            int m = mt * 16 + kg * 4 + r;
            float sc = scale_g[m], sh = shift_g[m];
            float v0 = acc[mt][0][r] * sc + sh;
            float v1 = acc[mt][1][r] * sc + sh;
            size_t orow = (size_t)(b * 64 + m) * HW + p0 + wid * 32 + ln;
            out[orow] = v0;
            out[orow + 16] = v1;
            float vs = v0 + v1;
            vs += __shfl_xor(vs, 1, 16);
            vs += __shfl_xor(vs, 2, 16);
            vs += __shfl_xor(vs, 4, 16);
            vs += __shfl_xor(vs, 8, 16);
            if (ln == 0) red[m * 4 + wid] = vs;
        }
    }
    __syncthreads();
    if (tid < 64)
        partial[tid * 1152 + tile] = red[tid * 4 + 0] + red[tid * 4 + 1] +
                                     red[tid * 4 + 2] + red[tid * 4 + 3];
}

// ============ KR: parallel partial reduce -> pooled mean ============
__global__ void reduce_kernel(const float* __restrict__ partial, float* __restrict__ pooled) {
    int o = blockIdx.x & 63, b = blockIdx.x >> 6;
    const float* pr = partial + o * 1152 + b * 288;
    int t = threadIdx.x;
    float s = 0.f;
    for (int q = t; q < 288; q += 64) s += pr[q];
#pragma unroll
    for (int d = 1; d < 64; d <<= 1) s += __shfl_xor(s, d, 64);
    if (t == 0) pooled[b * 64 + o] = s * (1.0f / (float)HW);
}

// ============ K3: SE MLP -> cw; per-batch bf16 tap-GEMM weights ============
// we_bf[b][t][c] = cw[b,c] * sa_w[c, t]  (t = dy*7+dx < 49; rows 49..63 zero)
__global__ void ca_kernel(const float* __restrict__ pooled_g,
                          const float* __restrict__ w1, const float* __restrict__ b1,
                          const float* __restrict__ w2, const float* __restrict__ b2,
                          const float* __restrict__ saw, float* __restrict__ cw,
                          ushort_t* __restrict__ we_bf) {
    __shared__ float pooled[256];
    __shared__ float t1[16];
    int t = threadIdx.x;
    int b = t >> 6, o = t & 63;
    pooled[t] = pooled_g[t];
    __syncthreads();
    if (t < 16) {
        int bb = t >> 2, hh = t & 3;
        float a = b1[hh];
        for (int c = 0; c < 64; ++c) a += pooled[bb * 64 + c] * w1[hh * 64 + c];
        t1[t] = fmaxf(a, 0.f);
    }
    __syncthreads();
    float a = b2[o];
#pragma unroll
    for (int h2 = 0; h2 < 4; ++h2) a += t1[b * 4 + h2] * w2[o * 4 + h2];
    float cwv = 1.f / (1.f + __expf(-a));
    cw[t] = cwv;
    for (int tap = 0; tap < 64; ++tap) {
        float v = (tap < 49) ? cwv * saw[o * 49 + tap] : 0.f;
        we_bf[(b * 64 + tap) * 64 + o] = f2bf(v);
    }
}

// ============ K4a: tap GEMM  u[b][t][p] = sum_c we_bf[b][t][c] * h[b][c][p] ============
__global__ __launch_bounds__(256) void tap_gemm_kernel(
    const float* __restrict__ h, const ushort_t* __restrict__ we_bf,
    ushort_t* __restrict__ u) {
    int tid = threadIdx.x;
    int b = blockIdx.y;
    int p0 = blockIdx.x * 128;
    int wid = tid >> 6, lane = tid & 63, ln = lane & 15, kg = lane >> 4;
    int pA = p0 + wid * 32 + ln, pB = pA + 16;
    const float* hb = h + (size_t)b * 64 * HW;
    const ushort_t* wt = we_bf + b * 4096;

    f32x4 acc[4][2];
#pragma unroll
    for (int mt = 0; mt < 4; ++mt)
#pragma unroll
        for (int nt = 0; nt < 2; ++nt) acc[mt][nt] = (f32x4){0.f, 0.f, 0.f, 0.f};

#pragma unroll
    for (int ks = 0; ks < 2; ++ks) {
        int ch = ks * 32 + kg * 8;
        short8 fA, fB;
#pragma unroll
        for (int q = 0; q < 8; ++q) {
            fA[q] = (short)f2bf(hb[(size_t)(ch + q) * HW + pA]);
            fB[q] = (short)f2bf(hb[(size_t)(ch + q) * HW + pB]);
        }
        short8 a0 = *(const short8*)(wt + (0 + ln) * 64 + ch);
        short8 a1 = *(const short8*)(wt + (16 + ln) * 64 + ch);
        short8 a2 = *(const short8*)(wt + (32 + ln) * 64 + ch);
        short8 a3 = *(const short8*)(wt + (48 + ln) * 64 + ch);
        acc[0][0] = __builtin_amdgcn_mfma_f32_16x16x32_bf16(a0, fA, acc[0][0], 0, 0, 0);
        acc[0][1] = __builtin_amdgcn_mfma_f32_16x16x32_bf16(a0, fB, acc[0][1], 0, 0, 0);
        acc[1][0] = __builtin_amdgcn_mfma_f32_16x16x32_bf16(a1, fA, acc[1][0], 0, 0, 0);
        acc[1][1] = __builtin_amdgcn_mfma_f32_16x16x32_bf16(a1, fB, acc[1][1], 0, 0, 0);
        acc[2][0] = __builtin_amdgcn_mfma_f32_16x16x32_bf16(a2, fA, acc[2][0], 0, 0, 0);
        acc[2][1] = __builtin_amdgcn_mfma_f32_16x16x32_bf16(a2, fB, acc[2][1], 0, 0, 0);
        acc[3][0] = __builtin_amdgcn_mfma_f32_16x16x32_bf16(a3, fA, acc[3][0], 0, 0, 0);
        acc[3][1] = __builtin_amdgcn_mfma_f32_16x16x32_bf16(a3, fB, acc[3][1], 0, 0, 0);
    }
#pragma unroll
    for (int mt = 0; mt < 4; ++mt)
#pragma unroll
        for (int r = 0; r < 4; ++r) {
            int m = mt * 16 + kg * 4 + r;
            if (m < 49) {
                ushort_t* up = u + (size_t)(b * 49 + m) * HW;
                up[pA] = f2bf(acc[mt][0][r]);
                up[pB] = f2bf(acc[mt][1][r]);
            }
        }
}

// ============ K4b: shift-add 49 taps -> sigmoid -> out *= cw*sw (fused final) ============
__global__ __launch_bounds__(256) void sa_final_kernel(
    float* __restrict__ out, const ushort_t* __restrict__ u,
    const float* __restrict__ cw, const float* __restrict__ sab) {
    __shared__ float cw_l[64];
    int tid = threadIdx.x;
    int b = blockIdx.y;
    int p = blockIdx.x * 256 + tid;
    if (tid < 64) cw_l[tid] = cw[b * 64 + tid];
    __syncthreads();
    int y = p / 192, x = p - y * 192;
    float s = sab[0];
    const ushort_t* ub = u + (size_t)b * 49 * HW;
#pragma unroll
    for (int dy = 0; dy < 7; ++dy)
#pragma unroll
        for (int dx = 0; dx < 7; ++dx) {
            int yy = y + dy - 3, xx = x + dx - 3;
            bool ok = ((unsigned)yy < 192u) && ((unsigned)xx < 192u);
            int ad = ok ? (p + (dy - 3) * 192 + (dx - 3)) : 0;
            float v = bflo((uint_t)ub[(size_t)(dy * 7 + dx) * HW + ad]);
            s += ok ? v : 0.f;
        }
    float swv = 1.f / (1.f + __expf(-s));
#pragma unroll 8
    for (int c = 0; c < 64; ++c) {
        size_t ix = (size_t)(b * 64 + c) * HW + p;
        out[ix] = out[ix] * (cw_l[c] * swv);
    }
}

extern "C" void kernel_launch(void* const* d_in, const int* in_sizes, int n_in,
                              void* d_out, int out_size, void* d_ws, size_t ws_size,
                              hipStream_t stream) {
    const float* x     = (const float*)d_in[0];
    const float* off_w = (const float*)d_in[1];
    const float* off_b = (const float*)d_in[2];
    const float* dw    = (const float*)d_in[3];
    const float* db    = (const float*)d_in[4];
    const float* bn_g  = (const float*)d_in[5];
    const float* bn_b  = (const float*)d_in[6];
    const float* bn_m  = (const float*)d_in[7];
    const float* bn_v  = (const float*)d_in[8];
    const float* ca_w1 = (const float*)d_in[9];
    const float* ca_b1 = (const float*)d_in[10];
    const float* ca_w2 = (const float*)d_in[11];
    const float* ca_b2 = (const float*)d_in[12];
    const float* sa_w  = (const float*)d_in[13];
    const float* sa_b  = (const float*)d_in[14];
    float* out = (float*)d_out;
    float* ws  = (float*)d_ws;

    // ws layout (floats):
    // x_t  [B,HW,64] bf16   @ 0        (9437184 sh = 4718592 fl)
    //   u  [B,49,HW] bf16   @ 0        (aliases x_t; x_t dead after deform)
    // w_bf                  @ 4718592  (18432 sh)
    // w_off                 @ 4737024  (18432 sh)
    // scale @4746240  shift @4746304  cw @4746368  pooled @4746624
    // partial [64][1152]    @ 4746880  (73728 fl)
    // we_bf [B][64][64] sh  @ 4820608  (16384 sh = 8192 fl)  -> end 4828800 fl = 19.3 MB
    ushort_t* x_t    = (ushort_t*)ws;
    ushort_t* u      = (ushort_t*)ws;
    ushort_t* w_bf   = (ushort_t*)(ws + 4718592);
    ushort_t* w_off  = (ushort_t*)(ws + 4737024);
    float* scale     = ws + 4746240;
    float* shift     = ws + 4746304;
    float* cw        = ws + 4746368;
    float* pooled    = ws + 4746624;
    float* partial   = ws + 4746880;
    ushort_t* we_bf  = (ushort_t*)(ws + 4820608);

    prep_kernel<<<216, 256, 0, stream>>>(dw, db, bn_g, bn_b, bn_m, bn_v, off_w,
                                         w_bf, w_off, scale, shift);
    transpose_kernel<<<576, 256, 0, stream>>>(x, x_t);
    deform_fused_kernel<<<1152, 256, 0, stream>>>(x_t, w_off, off_b, w_bf,
                                                  scale, shift, out, partial);
    reduce_kernel<<<256, 64, 0, stream>>>(partial, pooled);
    ca_kernel<<<1, 256, 0, stream>>>(pooled, ca_w1, ca_b1, ca_w2, ca_b2, sa_w, cw, we_bf);
    tap_gemm_kernel<<<dim3(288, 4), 256, 0, stream>>>(out, we_bf, u);
    sa_final_kernel<<<dim3(144, 4), 256, 0, stream>>>(out, u, cw, sa_b);
}